// Round 5
// baseline (466.553 us; speedup 1.0000x reference)
//
#include <hip/hip_runtime.h>
#include <hip/hip_bf16.h>

#define B_  4
#define L_  4096
#define DM_ 1024
#define DK_ 128
#define DV_ 128
#define KS_ 4
#define ROWS_ (B_ * L_)            // 16384

typedef __bf16 bf16x8 __attribute__((ext_vector_type(8)));
typedef float  f32x4  __attribute__((ext_vector_type(4)));

// raw barrier: lgkm drain only — in-flight global prefetches stay outstanding
#define BAR_LGKM() __asm__ volatile("s_waitcnt lgkmcnt(0)\ns_barrier" ::: "memory")

// max-reduce over the 16-lane DPP row via row_ror 1,2,4,8 (pure VALU, no LDS)
__device__ __forceinline__ float rowmax_dpp(float v) {
    int x;
    x = __float_as_int(v);
    v = fmaxf(v, __int_as_float(__builtin_amdgcn_update_dpp(x, x, 0x121, 0xF, 0xF, false)));
    x = __float_as_int(v);
    v = fmaxf(v, __int_as_float(__builtin_amdgcn_update_dpp(x, x, 0x122, 0xF, 0xF, false)));
    x = __float_as_int(v);
    v = fmaxf(v, __int_as_float(__builtin_amdgcn_update_dpp(x, x, 0x124, 0xF, 0xF, false)));
    x = __float_as_int(v);
    v = fmaxf(v, __int_as_float(__builtin_amdgcn_update_dpp(x, x, 0x128, 0xF, 0xF, false)));
    return v;
}

// ---------------------------------------------------------------------------
// Kernel 0: transpose+cast W -> WT bf16; WQ additionally scaled by 1/sqrt(dk).
// ---------------------------------------------------------------------------
__global__ __launch_bounds__(256) void wt_kernel(
    const float* __restrict__ WQ, const float* __restrict__ WK,
    const float* __restrict__ WV, __bf16* __restrict__ WT)
{
    const int mat = blockIdx.y;
    const float* W = (mat == 0) ? WQ : (mat == 1) ? WK : WV;
    const float scl = (mat == 0) ? 0.088388347648318447f : 1.0f;
    __bf16* Wt = WT + (size_t)mat * DK_ * DM_;

    __shared__ float lds[DK_][33];
    const int t  = threadIdx.x;
    const int d0 = blockIdx.x * 32;

    for (int i = 0; i < 16; ++i) {
        int idx = i * 256 + t;
        int dd = idx >> 7, n = idx & 127;
        lds[n][dd] = W[(size_t)(d0 + dd) * DK_ + n] * scl;
    }
    __syncthreads();
    for (int i = 0; i < 16; ++i) {
        int idx = i * 256 + t;
        int n = idx >> 5, dd = idx & 31;
        Wt[(size_t)n * DM_ + d0 + dd] = (__bf16)lds[n][dd];
    }
}

// ---------------------------------------------------------------------------
// Kernel 1: projections with software-pipelined WT staging (prefetch next
// chunk into VGPRs; raw lgkm-only barriers keep prefetch in flight).
// Staging decomposition: row = i*16 + (t>>4), col = (t&15)*8 elements.
// ---------------------------------------------------------------------------
__global__ __launch_bounds__(256) void proj_kernel(
    const float* __restrict__ Q, const float* __restrict__ K, const float* __restrict__ V,
    const __bf16* __restrict__ WT,
    __bf16* __restrict__ qb, __bf16* __restrict__ kb, __bf16* __restrict__ vT)
{
    const int mat = blockIdx.y;
    const float* X = (mat == 0) ? Q : (mat == 1) ? K : V;
    const __bf16* Wt = WT + (size_t)mat * DK_ * DM_;

    __shared__ __bf16 w_lds[128][132];            // 33792 B

    const int t    = threadIdx.x;
    const int w    = t >> 6;
    const int l    = t & 63;
    const int quad = l >> 4;
    const int c16  = l & 15;
    const int m0   = blockIdx.x * 64 + w * 16;
    const float* xrow = &X[(size_t)(m0 + c16) * DM_];

    const int sn  = t >> 4;                       // row base 0..15
    const int sb8 = (t & 15) << 3;                // col (elements), 16B aligned

    f32x4 acc[8];
    for (int i = 0; i < 8; ++i) acc[i] = {0.f, 0.f, 0.f, 0.f};

    int4 wreg[8];
    for (int i = 0; i < 8; ++i)
        wreg[i] = *(const int4*)&Wt[(size_t)(i * 16 + sn) * DM_ + sb8];

    for (int kt8 = 0; kt8 < 8; ++kt8) {
        const int d0 = kt8 * 128;
        BAR_LGKM();                               // prior frag reads done
        for (int i = 0; i < 8; ++i)               // write chunk kt8 (vmcnt auto)
            *(int4*)&w_lds[i * 16 + sn][sb8] = wreg[i];
        if (kt8 < 7)
            for (int i = 0; i < 8; ++i)           // prefetch chunk kt8+1
                wreg[i] = *(const int4*)&Wt[(size_t)(i * 16 + sn) * DM_ + d0 + 128 + sb8];
        BAR_LGKM();                               // writes visible

        for (int dd = 0; dd < 4; ++dd) {
            const float* xp = xrow + d0 + dd * 32 + quad * 8;
            float4 x0 = *(const float4*)xp;
            float4 x1 = *(const float4*)(xp + 4);
            bf16x8 af;
            af[0] = (__bf16)x0.x; af[1] = (__bf16)x0.y; af[2] = (__bf16)x0.z; af[3] = (__bf16)x0.w;
            af[4] = (__bf16)x1.x; af[5] = (__bf16)x1.y; af[6] = (__bf16)x1.z; af[7] = (__bf16)x1.w;
            for (int nt = 0; nt < 8; ++nt) {
                bf16x8 bfv = *(const bf16x8*)&w_lds[nt * 16 + c16][dd * 32 + quad * 8];
                acc[nt] = __builtin_amdgcn_mfma_f32_16x16x32_bf16(af, bfv, acc[nt], 0, 0, 0);
            }
        }
    }

    if (mat < 2) {
        __bf16* outp = (mat == 0) ? qb : kb;
        for (int nt = 0; nt < 8; ++nt)
            for (int r = 0; r < 4; ++r)
                outp[(size_t)(m0 + quad * 4 + r) * DK_ + nt * 16 + c16] = (__bf16)acc[nt][r];
    } else {
        for (int nt = 0; nt < 8; ++nt)
            for (int r = 0; r < 4; ++r) {
                int row = m0 + quad * 4 + r;
                int b = row >> 12, s = row & (L_ - 1);
                vT[((size_t)b * DV_ + nt * 16 + c16) * L_ + s] = (__bf16)acc[nt][r];
            }
    }
}

// ---------------------------------------------------------------------------
// Kernel 2: flash attention, pipelined. Correct staging decomposition:
//   K tile 64x128: row = i*16 + (t>>4),  col = (t&15)*8   (4 int4/thread)
//   V tile 128x64: row = i*32 + (t>>3),  col = (t&7)*8    (4 int4/thread)
// ---------------------------------------------------------------------------
__global__ __launch_bounds__(256) void attn_kernel(
    const __bf16* __restrict__ qb, const __bf16* __restrict__ kb,
    const __bf16* __restrict__ vT, const int* __restrict__ mask,
    __bf16* __restrict__ ob_part, float* __restrict__ ml_part)
{
    __shared__ __bf16 k_lds[64][140];      // 17920 B
    __shared__ __bf16 v_lds[128][76];      // 19456 B
    __shared__ __bf16 p_lds[4][16][76];    //  9728 B  (total 47104 -> 3 blk/CU)

    const int t    = threadIdx.x;
    const int w    = t >> 6;
    const int l    = t & 63;
    const int quad = l >> 4;
    const int c16  = l & 15;

    const int combo = blockIdx.x & 15;     // XCD pinning: 1 batch x 2 ranges/XCD
    const int b     = combo & 3;
    const int ks    = combo >> 2;
    const int qt    = blockIdx.x >> 4;
    const int m0    = qt * 64 + w * 16;
    const size_t bL = (size_t)b * L_;
    const int kbase = ks * (L_ / KS_);

    const int skr = t >> 4, skc = (t & 15) << 3;   // K staging (row base, col elems)
    const int svr = t >> 3, svc = (t & 7) << 3;    // V staging

    bf16x8 qf[4];
    {
        const __bf16* qrow = &qb[(bL + m0 + c16) * DK_];
        for (int dt = 0; dt < 4; ++dt)
            qf[dt] = *(const bf16x8*)&qrow[dt * 32 + quad * 8];
    }

    // mask ballot prologue: bit sc set iff all 64 keys of chunk sc are valid
    unsigned int mbits = 0;
    for (int sc = 0; sc < 16; ++sc) {
        int mv = mask[bL + kbase + sc * 64 + l];
        mbits |= (unsigned int)(__ballot(mv == 1) == ~0ull) << sc;
    }

    bf16x8 onesv;
    for (int i = 0; i < 8; ++i) onesv[i] = (__bf16)1.0f;

    f32x4 o[8], osum;
    for (int i = 0; i < 8; ++i) o[i] = {0.f, 0.f, 0.f, 0.f};
    osum = {0.f, 0.f, 0.f, 0.f};
    float mst[4];
    for (int r = 0; r < 4; ++r) mst[r] = -1e30f;

    // prefetch chunk 0 into regs
    int4 kreg[4], vreg[4];
    {
        const __bf16* kp = &kb[(bL + kbase + skr) * DK_ + skc];
        for (int i = 0; i < 4; ++i)
            kreg[i] = *(const int4*)&kp[(size_t)i * 16 * DK_];
        const __bf16* vp = &vT[((size_t)b * DV_ + svr) * L_ + kbase + svc];
        for (int i = 0; i < 4; ++i)
            vreg[i] = *(const int4*)&vp[(size_t)i * 32 * L_];
    }

    for (int sc = 0; sc < (L_ / KS_) / 64; ++sc) {
        const int s0 = kbase + sc * 64;

        BAR_LGKM();                         // prior chunk's frag reads done
        for (int i = 0; i < 4; ++i)         // write chunk sc (vmcnt auto)
            *(int4*)&k_lds[i * 16 + skr][skc] = kreg[i];
        for (int i = 0; i < 4; ++i)
            *(int4*)&v_lds[i * 32 + svr][svc] = vreg[i];
        if (sc < 15) {                      // prefetch chunk sc+1 (stays in flight)
            const __bf16* kp = &kb[(bL + s0 + 64 + skr) * DK_ + skc];
            for (int i = 0; i < 4; ++i)
                kreg[i] = *(const int4*)&kp[(size_t)i * 16 * DK_];
            const __bf16* vp = &vT[((size_t)b * DV_ + svr) * L_ + s0 + 64 + svc];
            for (int i = 0; i < 4; ++i)
                vreg[i] = *(const int4*)&vp[(size_t)i * 32 * L_];
        }
        BAR_LGKM();                         // writes visible

        // ---- S = q . k^T  (q pre-scaled by 1/sqrt(dk)) ----
        f32x4 sacc[4];
        for (int nt = 0; nt < 4; ++nt) sacc[nt] = {0.f, 0.f, 0.f, 0.f};
        for (int dt = 0; dt < 4; ++dt)
            for (int nt = 0; nt < 4; ++nt) {
                bf16x8 kf = *(const bf16x8*)&k_lds[nt * 16 + c16][dt * 32 + quad * 8];
                sacc[nt] = __builtin_amdgcn_mfma_f32_16x16x32_bf16(qf[dt], kf, sacc[nt], 0, 0, 0);
            }

        if (!((mbits >> sc) & 1)) {         // slow path (never in this bench)
            for (int nt = 0; nt < 4; ++nt) {
                int mk = mask[bL + s0 + nt * 16 + c16];
                for (int r = 0; r < 4; ++r)
                    if (mk != 1) sacc[nt][r] = -1e30f;
            }
        }

        // ---- online softmax: DPP max-reduce; lazy rescale ----
        float nm[4];
        bool up = false;
        for (int r = 0; r < 4; ++r) {
            float cm = fmaxf(fmaxf(sacc[0][r], sacc[1][r]), fmaxf(sacc[2][r], sacc[3][r]));
            cm = rowmax_dpp(cm);
            nm[r] = fmaxf(mst[r], cm);
            up |= (nm[r] > mst[r]);
        }
        if (__ballot(up)) {
            float alpha[4];
            for (int r = 0; r < 4; ++r) {
                alpha[r] = __expf(mst[r] - nm[r]);
                mst[r] = nm[r];
            }
            for (int vt = 0; vt < 8; ++vt)
                for (int r = 0; r < 4; ++r) o[vt][r] *= alpha[r];
            for (int r = 0; r < 4; ++r) osum[r] *= alpha[r];
        }

        for (int r = 0; r < 4; ++r)
            for (int nt = 0; nt < 4; ++nt) {
                float p = __expf(sacc[nt][r] - nm[r]);
                p_lds[w][quad * 4 + r][nt * 16 + c16] = (__bf16)p;
            }
        __asm__ volatile("s_waitcnt lgkmcnt(0)" ::: "memory");  // P visible (wave-local)

        // ---- O += P.V ; osum += P.1 (denominator via ones-column MFMA) ----
        for (int kt = 0; kt < 2; ++kt) {
            bf16x8 pf = *(const bf16x8*)&p_lds[w][c16][kt * 32 + quad * 8];
            for (int vt = 0; vt < 8; ++vt) {
                bf16x8 vf = *(const bf16x8*)&v_lds[vt * 16 + c16][kt * 32 + quad * 8];
                o[vt] = __builtin_amdgcn_mfma_f32_16x16x32_bf16(pf, vf, o[vt], 0, 0, 0);
            }
            osum = __builtin_amdgcn_mfma_f32_16x16x32_bf16(pf, onesv, osum, 0, 0, 0);
        }
    }

    // ---- write this split's partial (unnormalized o, m, l=osum) ----
    __bf16* op = ob_part + ((size_t)ks * ROWS_ + bL + m0) * DV_;
    for (int vt = 0; vt < 8; ++vt)
        for (int r = 0; r < 4; ++r)
            op[(size_t)(quad * 4 + r) * DV_ + vt * 16 + c16] = (__bf16)o[vt][r];
    if (c16 == 0)
        for (int r = 0; r < 4; ++r) {
            size_t row = (size_t)ks * ROWS_ + bL + m0 + quad * 4 + r;
            ml_part[row * 2 + 0] = mst[r];
            ml_part[row * 2 + 1] = osum[r];
        }
}

// ---------------------------------------------------------------------------
// Kernel 3: combine KS partials.
// ---------------------------------------------------------------------------
__global__ __launch_bounds__(256) void combine_kernel(
    const __bf16* __restrict__ ob_part, const float* __restrict__ ml_part,
    float* __restrict__ out)
{
    const int gid = blockIdx.x * 256 + threadIdx.x;
    const int row = gid >> 5;
    const int c4  = (gid & 31) << 2;

    float m[KS_], lv[KS_];
    float M = -1e30f;
    for (int s = 0; s < KS_; ++s) {
        m[s]  = ml_part[((size_t)s * ROWS_ + row) * 2 + 0];
        lv[s] = ml_part[((size_t)s * ROWS_ + row) * 2 + 1];
        M = fmaxf(M, m[s]);
    }
    float Lt = 0.f, acc[4] = {0.f, 0.f, 0.f, 0.f};
    for (int s = 0; s < KS_; ++s) {
        float ws = __expf(m[s] - M);
        Lt += lv[s] * ws;
        const __bf16* op = ob_part + ((size_t)s * ROWS_ + row) * DV_ + c4;
        for (int c = 0; c < 4; ++c) acc[c] += (float)op[c] * ws;
    }
    float rL = 1.0f / Lt;
    for (int c = 0; c < 4; ++c)
        out[(size_t)row * DV_ + c4 + c] = acc[c] * rL;
}

extern "C" void kernel_launch(void* const* d_in, const int* in_sizes, int n_in,
                              void* d_out, int out_size, void* d_ws, size_t ws_size,
                              hipStream_t stream) {
    const float* Q    = (const float*)d_in[0];
    const float* K    = (const float*)d_in[1];
    const float* V    = (const float*)d_in[2];
    const int*   mask = (const int*)d_in[3];
    const float* WQ   = (const float*)d_in[4];
    const float* WK   = (const float*)d_in[5];
    const float* WV   = (const float*)d_in[6];
    float* out = (float*)d_out;

    __bf16* qb = (__bf16*)d_ws;
    __bf16* kb = qb + (size_t)ROWS_ * DK_;
    __bf16* vT = kb + (size_t)ROWS_ * DK_;
    __bf16* WT = vT + (size_t)ROWS_ * DV_;
    __bf16* ob_part = WT + (size_t)3 * DK_ * DM_;
    float*  ml_part = (float*)(ob_part + (size_t)KS_ * ROWS_ * DV_);

    wt_kernel<<<dim3(DM_ / 32, 3), 256, 0, stream>>>(WQ, WK, WV, WT);
    proj_kernel<<<dim3(ROWS_ / 64, 3), 256, 0, stream>>>(Q, K, V, WT, qb, kb, vT);
    attn_kernel<<<dim3((ROWS_ / 64) * KS_), 256, 0, stream>>>(qb, kb, vT, mask, ob_part, ml_part);
    combine_kernel<<<dim3(ROWS_ * 32 / 256), 256, 0, stream>>>(ob_part, ml_part, out);
}

// Round 7
// 287.278 us; speedup vs baseline: 1.6240x; 1.6240x over previous
//
#include <hip/hip_runtime.h>
#include <hip/hip_bf16.h>

#define B_  4
#define L_  4096
#define DM_ 1024
#define DK_ 128
#define DV_ 128
#define KS_ 4
#define ROWS_ (B_ * L_)            // 16384

typedef __bf16 bf16x8 __attribute__((ext_vector_type(8)));
typedef float  f32x4  __attribute__((ext_vector_type(4)));

// async global->LDS DMA, 16 B per lane, no VGPR round-trip.
// LDS dest is wave-uniform base + lane*16; gsrc is per-lane.
__device__ __forceinline__ void dma16(const void* g, void* l) {
    __builtin_amdgcn_global_load_lds(
        (const __attribute__((address_space(1))) void*)g,
        (__attribute__((address_space(3))) void*)l, 16, 0, 0);
}

// order-independent: drain ALL vmem (DMAs + any reg prefetch) + LDS, barrier.
#define WAITBAR0() __asm__ volatile("s_waitcnt vmcnt(0) lgkmcnt(0)\ns_barrier" ::: "memory")

// max-reduce over the 16-lane group via DPP row_ror (pure VALU)
__device__ __forceinline__ float rowmax_dpp(float v) {
    int x;
    x = __float_as_int(v);
    v = fmaxf(v, __int_as_float(__builtin_amdgcn_update_dpp(x, x, 0x121, 0xF, 0xF, false)));
    x = __float_as_int(v);
    v = fmaxf(v, __int_as_float(__builtin_amdgcn_update_dpp(x, x, 0x122, 0xF, 0xF, false)));
    x = __float_as_int(v);
    v = fmaxf(v, __int_as_float(__builtin_amdgcn_update_dpp(x, x, 0x124, 0xF, 0xF, false)));
    x = __float_as_int(v);
    v = fmaxf(v, __int_as_float(__builtin_amdgcn_update_dpp(x, x, 0x128, 0xF, 0xF, false)));
    return v;
}

// ---------------------------------------------------------------------------
// Kernel 0: transpose+cast W -> WT bf16; WQ pre-scaled by 1/sqrt(dk).
// ---------------------------------------------------------------------------
__global__ __launch_bounds__(256) void wt_kernel(
    const float* __restrict__ WQ, const float* __restrict__ WK,
    const float* __restrict__ WV, __bf16* __restrict__ WT)
{
    const int mat = blockIdx.y;
    const float* W = (mat == 0) ? WQ : (mat == 1) ? WK : WV;
    const float scl = (mat == 0) ? 0.088388347648318447f : 1.0f;
    __bf16* Wt = WT + (size_t)mat * DK_ * DM_;

    __shared__ float lds[DK_][33];
    const int t  = threadIdx.x;
    const int d0 = blockIdx.x * 32;

    for (int i = 0; i < 16; ++i) {
        int idx = i * 256 + t;
        int dd = idx >> 7, n = idx & 127;
        lds[n][dd] = W[(size_t)(d0 + dd) * DK_ + n] * scl;
    }
    __syncthreads();
    for (int i = 0; i < 16; ++i) {
        int idx = i * 256 + t;
        int n = idx >> 5, dd = idx & 31;
        Wt[(size_t)n * DM_ + d0 + dd] = (__bf16)lds[n][dd];
    }
}

// ---------------------------------------------------------------------------
// Kernel 1: projections. BK=64 W-tiles staged by async DMA into a
// double-buffered XOR-swizzled LDS; X prefetched to regs one chunk ahead.
// ALL barriers are vmcnt(0): correctness independent of DMA/load issue order
// (vmcnt(4) in R6 broke when the compiler hoisted X loads above the DMAs).
// ---------------------------------------------------------------------------
__global__ __launch_bounds__(256, 4) void proj_kernel(
    const float* __restrict__ Q, const float* __restrict__ K, const float* __restrict__ V,
    const __bf16* __restrict__ WT,
    __bf16* __restrict__ qb, __bf16* __restrict__ kb, __bf16* __restrict__ vT)
{
    const int mat = blockIdx.y;
    const float* X = (mat == 0) ? Q : (mat == 1) ? K : V;
    const __bf16* Wt = WT + (size_t)mat * DK_ * DM_;

    __shared__ __bf16 wbuf[2][128 * 64];          // 16 KB x2 -> 4 blocks/CU

    const int t    = threadIdx.x;
    const int w    = t >> 6;
    const int l    = t & 63;
    const int quad = l >> 4;
    const int c16  = l & 15;
    const int m0   = blockIdx.x * 64 + w * 16;
    const float* xrow = &X[(size_t)(m0 + c16) * DM_];

    // DMA sources: instr i covers row (w*4+i)*8 + (l>>3), phys colblk l&7,
    // fetched logical colblk = phys ^ (row&7)  [XOR swizzle]
    const __bf16* wg[4];
    for (int i = 0; i < 4; ++i) {
        int row = (w * 4 + i) * 8 + (l >> 3);
        int lc  = (l & 7) ^ (row & 7);
        wg[i] = Wt + (size_t)row * DM_ + lc * 8;
    }

    f32x4 acc[8];
    for (int i = 0; i < 8; ++i) acc[i] = {0.f, 0.f, 0.f, 0.f};

    // prologue: DMA chunk 0 + X chunk 0 prefetch; full drain barrier
    for (int i = 0; i < 4; ++i)
        dma16(wg[i], &wbuf[0][(w * 4 + i) * 512]);
    float4 xn[4];
    for (int dd = 0; dd < 2; ++dd)
        for (int p = 0; p < 2; ++p)
            xn[dd * 2 + p] = *(const float4*)(xrow + dd * 32 + quad * 8 + p * 4);
    WAITBAR0();

    for (int kt = 0; kt < 16; ++kt) {              // BK = 64
        const int cur = kt & 1, nxt = cur ^ 1;
        float4 xc[4];
        for (int i = 0; i < 4; ++i) xc[i] = xn[i]; // consume prefetch
        if (kt < 15) {
            const int d1 = (kt + 1) * 64;
            for (int i = 0; i < 4; ++i)
                dma16(wg[i] + d1, &wbuf[nxt][(w * 4 + i) * 512]);
            for (int dd = 0; dd < 2; ++dd)
                for (int p = 0; p < 2; ++p)
                    xn[dd * 2 + p] = *(const float4*)(xrow + d1 + dd * 32 + quad * 8 + p * 4);
        }

        for (int dd = 0; dd < 2; ++dd) {
            float4 x0 = xc[dd * 2], x1 = xc[dd * 2 + 1];
            bf16x8 af;
            af[0] = (__bf16)x0.x; af[1] = (__bf16)x0.y; af[2] = (__bf16)x0.z; af[3] = (__bf16)x0.w;
            af[4] = (__bf16)x1.x; af[5] = (__bf16)x1.y; af[6] = (__bf16)x1.z; af[7] = (__bf16)x1.w;
            for (int nt = 0; nt < 8; ++nt) {
                bf16x8 bfv = *(const bf16x8*)
                    &wbuf[cur][(nt * 16 + c16) * 64 + (((dd * 4 + quad) ^ (c16 & 7)) << 3)];
                acc[nt] = __builtin_amdgcn_mfma_f32_16x16x32_bf16(af, bfv, acc[nt], 0, 0, 0);
            }
        }
        if (kt < 15) WAITBAR0();                   // full drain: order-safe
    }

    // C/D: row = quad*4+r, col = c16 + 16*nt
    if (mat < 2) {
        __bf16* outp = (mat == 0) ? qb : kb;
        for (int nt = 0; nt < 8; ++nt)
            for (int r = 0; r < 4; ++r)
                outp[(size_t)(m0 + quad * 4 + r) * DK_ + nt * 16 + c16] = (__bf16)acc[nt][r];
    } else {
        for (int nt = 0; nt < 8; ++nt)
            for (int r = 0; r < 4; ++r) {
                int row = m0 + quad * 4 + r;
                int b = row >> 12, s = row & (L_ - 1);
                vT[((size_t)b * DV_ + nt * 16 + c16) * L_ + s] = (__bf16)acc[nt][r];
            }
    }
}

// ---------------------------------------------------------------------------
// Kernel 2: flash attention. K/V tiles staged via async DMA into
// double-buffered XOR-swizzled LDS (K: cb^=row&15, V: cb^=row&7); one
// vmcnt(0)+barrier per chunk; next-chunk DMAs in flight across compute.
// ---------------------------------------------------------------------------
__global__ __launch_bounds__(256, 2) void attn_kernel(
    const __bf16* __restrict__ qb, const __bf16* __restrict__ kb,
    const __bf16* __restrict__ vT, const int* __restrict__ mask,
    __bf16* __restrict__ ob_part, float* __restrict__ ml_part)
{
    __shared__ __bf16 kbuf[2][64 * 128];   // 16 KB x2
    __shared__ __bf16 vbuf[2][128 * 64];   // 16 KB x2
    __shared__ __bf16 p_lds[4][16 * 76];   // 9728 B  (total 75264 -> 2 blk/CU)

    const int t    = threadIdx.x;
    const int w    = t >> 6;
    const int l    = t & 63;
    const int quad = l >> 4;
    const int c16  = l & 15;

    const int combo = blockIdx.x & 15;     // XCD pinning: 1 batch x 2 ranges/XCD
    const int b     = combo & 3;
    const int ks    = combo >> 2;
    const int qt    = blockIdx.x >> 4;
    const int m0    = qt * 64 + w * 16;
    const size_t bL = (size_t)b * L_;
    const int kbase = ks * (L_ / KS_);

    // DMA source pointers (XOR-swizzled so frag reads are 2-way/free)
    const __bf16* kg[4];
    const __bf16* vg[4];
    for (int i = 0; i < 4; ++i) {
        int kr  = (w * 4 + i) * 4 + (l >> 4);          // 0..63
        int klc = (l & 15) ^ (kr & 15);
        kg[i] = kb + (bL + kbase + kr) * DK_ + klc * 8;
        int vr  = (w * 4 + i) * 8 + (l >> 3);          // 0..127
        int vlc = (l & 7) ^ (vr & 7);
        vg[i] = vT + ((size_t)b * DV_ + vr) * L_ + kbase + vlc * 8;
    }

    bf16x8 qf[4];
    {
        const __bf16* qrow = &qb[(bL + m0 + c16) * DK_];
        for (int dt = 0; dt < 4; ++dt)
            qf[dt] = *(const bf16x8*)&qrow[dt * 32 + quad * 8];
    }

    // vectorized mask ballot: bit sc set iff all 64 keys of chunk sc valid
    unsigned int mbits = 0;
    for (int g = 0; g < 4; ++g) {
        const int4 mv = *(const int4*)&mask[bL + kbase + g * 256 + l * 4];
        bool ok = (mv.x == 1) && (mv.y == 1) && (mv.z == 1) && (mv.w == 1);
        unsigned long long bm = __ballot(ok);
        for (int cc = 0; cc < 4; ++cc)
            if (((bm >> (16 * cc)) & 0xFFFFull) == 0xFFFFull)
                mbits |= 1u << (g * 4 + cc);
    }

    bf16x8 onesv;
    for (int i = 0; i < 8; ++i) onesv[i] = (__bf16)1.0f;

    f32x4 o[8], osum;
    for (int i = 0; i < 8; ++i) o[i] = {0.f, 0.f, 0.f, 0.f};
    osum = {0.f, 0.f, 0.f, 0.f};
    float mst[4];
    for (int r = 0; r < 4; ++r) mst[r] = -1e30f;

    // prologue: DMA chunk 0 into buffer 0; full drain
    for (int i = 0; i < 4; ++i) dma16(kg[i], &kbuf[0][(w * 4 + i) * 512]);
    for (int i = 0; i < 4; ++i) dma16(vg[i], &vbuf[0][(w * 4 + i) * 512]);
    WAITBAR0();

    for (int sc = 0; sc < (L_ / KS_) / 64; ++sc) {   // 16 chunks
        const int cur = sc & 1, nxt = cur ^ 1;
        if (sc < 15) {                               // DMA chunk sc+1
            for (int i = 0; i < 4; ++i)
                dma16(kg[i] + (size_t)(sc + 1) * 64 * DK_, &kbuf[nxt][(w * 4 + i) * 512]);
            for (int i = 0; i < 4; ++i)
                dma16(vg[i] + (sc + 1) * 64, &vbuf[nxt][(w * 4 + i) * 512]);
        }

        // ---- S = q . k^T  (q pre-scaled by 1/sqrt(dk)) ----
        f32x4 sacc[4];
        for (int nt = 0; nt < 4; ++nt) sacc[nt] = {0.f, 0.f, 0.f, 0.f};
        for (int dt = 0; dt < 4; ++dt)
            for (int nt = 0; nt < 4; ++nt) {
                bf16x8 kf = *(const bf16x8*)
                    &kbuf[cur][(nt * 16 + c16) * 128 + (((dt * 4 + quad) ^ c16) << 3)];
                sacc[nt] = __builtin_amdgcn_mfma_f32_16x16x32_bf16(qf[dt], kf, sacc[nt], 0, 0, 0);
            }

        if (!((mbits >> sc) & 1)) {         // slow path (never in this bench)
            const int s0 = kbase + sc * 64;
            for (int nt = 0; nt < 4; ++nt) {
                int mk = mask[bL + s0 + nt * 16 + c16];
                for (int r = 0; r < 4; ++r)
                    if (mk != 1) sacc[nt][r] = -1e30f;
            }
        }

        // ---- online softmax: DPP max-reduce; lazy rescale ----
        float nm[4];
        bool up = false;
        for (int r = 0; r < 4; ++r) {
            float cm = fmaxf(fmaxf(sacc[0][r], sacc[1][r]), fmaxf(sacc[2][r], sacc[3][r]));
            cm = rowmax_dpp(cm);
            nm[r] = fmaxf(mst[r], cm);
            up |= (nm[r] > mst[r]);
        }
        if (__ballot(up)) {
            float alpha[4];
            for (int r = 0; r < 4; ++r) {
                alpha[r] = __expf(mst[r] - nm[r]);
                mst[r] = nm[r];
            }
            for (int vt = 0; vt < 8; ++vt)
                for (int r = 0; r < 4; ++r) o[vt][r] *= alpha[r];
            for (int r = 0; r < 4; ++r) osum[r] *= alpha[r];
        }

        for (int r = 0; r < 4; ++r)
            for (int nt = 0; nt < 4; ++nt) {
                float p = __expf(sacc[nt][r] - nm[r]);
                p_lds[w][(quad * 4 + r) * 76 + nt * 16 + c16] = (__bf16)p;
            }
        __asm__ volatile("s_waitcnt lgkmcnt(0)" ::: "memory");  // P visible (wave-local)

        // ---- O += P.V ; osum += P.1 ----
        for (int kt = 0; kt < 2; ++kt) {
            bf16x8 pf = *(const bf16x8*)&p_lds[w][c16 * 76 + kt * 32 + quad * 8];
            for (int vt = 0; vt < 8; ++vt) {
                bf16x8 vf = *(const bf16x8*)
                    &vbuf[cur][(vt * 16 + c16) * 64 + (((kt * 4 + quad) ^ (c16 & 7)) << 3)];
                o[vt] = __builtin_amdgcn_mfma_f32_16x16x32_bf16(pf, vf, o[vt], 0, 0, 0);
            }
            osum = __builtin_amdgcn_mfma_f32_16x16x32_bf16(pf, onesv, osum, 0, 0, 0);
        }

        if (sc < 15) WAITBAR0();            // next chunk's DMAs complete + barrier
    }

    // ---- write this split's partial (unnormalized o, m, l=osum) ----
    __bf16* op = ob_part + ((size_t)ks * ROWS_ + bL + m0) * DV_;
    for (int vt = 0; vt < 8; ++vt)
        for (int r = 0; r < 4; ++r)
            op[(size_t)(quad * 4 + r) * DV_ + vt * 16 + c16] = (__bf16)o[vt][r];
    if (c16 == 0)
        for (int r = 0; r < 4; ++r) {
            size_t row = (size_t)ks * ROWS_ + bL + m0 + quad * 4 + r;
            ml_part[row * 2 + 0] = mst[r];
            ml_part[row * 2 + 1] = osum[r];
        }
}

// ---------------------------------------------------------------------------
// Kernel 3: combine KS partials.
// ---------------------------------------------------------------------------
__global__ __launch_bounds__(256) void combine_kernel(
    const __bf16* __restrict__ ob_part, const float* __restrict__ ml_part,
    float* __restrict__ out)
{
    const int gid = blockIdx.x * 256 + threadIdx.x;
    const int row = gid >> 5;
    const int c4  = (gid & 31) << 2;

    float m[KS_], lv[KS_];
    float M = -1e30f;
    for (int s = 0; s < KS_; ++s) {
        m[s]  = ml_part[((size_t)s * ROWS_ + row) * 2 + 0];
        lv[s] = ml_part[((size_t)s * ROWS_ + row) * 2 + 1];
        M = fmaxf(M, m[s]);
    }
    float Lt = 0.f, acc[4] = {0.f, 0.f, 0.f, 0.f};
    for (int s = 0; s < KS_; ++s) {
        float ws = __expf(m[s] - M);
        Lt += lv[s] * ws;
        const __bf16* op = ob_part + ((size_t)s * ROWS_ + row) * DV_ + c4;
        for (int c = 0; c < 4; ++c) acc[c] += (float)op[c] * ws;
    }
    float rL = 1.0f / Lt;
    for (int c = 0; c < 4; ++c)
        out[(size_t)row * DV_ + c4 + c] = acc[c] * rL;
}

extern "C" void kernel_launch(void* const* d_in, const int* in_sizes, int n_in,
                              void* d_out, int out_size, void* d_ws, size_t ws_size,
                              hipStream_t stream) {
    const float* Q    = (const float*)d_in[0];
    const float* K    = (const float*)d_in[1];
    const float* V    = (const float*)d_in[2];
    const int*   mask = (const int*)d_in[3];
    const float* WQ   = (const float*)d_in[4];
    const float* WK   = (const float*)d_in[5];
    const float* WV   = (const float*)d_in[6];
    float* out = (float*)d_out;

    __bf16* qb = (__bf16*)d_ws;
    __bf16* kb = qb + (size_t)ROWS_ * DK_;
    __bf16* vT = kb + (size_t)ROWS_ * DK_;
    __bf16* WT = vT + (size_t)ROWS_ * DV_;
    __bf16* ob_part = WT + (size_t)3 * DK_ * DM_;
    float*  ml_part = (float*)(ob_part + (size_t)KS_ * ROWS_ * DV_);

    wt_kernel<<<dim3(DM_ / 32, 3), 256, 0, stream>>>(WQ, WK, WV, WT);
    proj_kernel<<<dim3(ROWS_ / 64, 3), 256, 0, stream>>>(Q, K, V, WT, qb, kb, vT);
    attn_kernel<<<dim3((ROWS_ / 64) * KS_), 256, 0, stream>>>(qb, kb, vT, mask, ob_part, ml_part);
    combine_kernel<<<dim3(ROWS_ * 32 / 256), 256, 0, stream>>>(ob_part, ml_part, out);
}